// Round 5
// baseline (93.404 us; speedup 1.0000x reference)
//
#include <hip/hip_runtime.h>

#define NN 1024
#define FF 128
#define FP 64
#define NH 2

// ws float offsets:
#define VT_OFF 0          // [H][FP][NN]  (X·W2)^T  — j-side, cross-block
#define H2_OFF 131072     // [H][NN][FP]  X·W2      — cross-block (aggregation)
#define SV_OFF 262144     // [H][NN]      sv = Σe ae·v — cross-block
#define FLAG_OFF (1 << 22) // flags at 16 MB into ws
#define GEN 0x9E3779B1u

// One kernel: 256 blocks (h x 128 i-tiles of 8) x 512 threads (8 waves).
// Phase 1: projections. Waves 0-3: u-path (W1, +bias) -> LDS only.
//          Waves 4-7: v-path (W2) -> global VT/H2/sv.
// Grid barrier (flag-based; falls through on warm replays).
// Phase 2: dense logits + sigmoid + normalize + sparse aggregation.
__global__ __launch_bounds__(512) void kFused(const float* __restrict__ X,
        const float* __restrict__ Ad, const float* __restrict__ W1,
        const float* __restrict__ W2, const float* __restrict__ b,
        const float* __restrict__ a, float* __restrict__ ws,
        float* __restrict__ out, float* __restrict__ att) {
    union Shm {
        float xs[8 * FF];                     // phase 1: X tile (4 KB)
        struct { float eval[8][256]; int eidx[8][256]; } p2;  // 16 KB
    };
    __shared__ Shm shm;
    __shared__ float s_u[FP][8];              // u-tile [e][row] (2 KB)
    __shared__ float s_h1[8][FP];             // H1 own rows (2 KB)
    __shared__ float s_ae[FP];
    __shared__ float s_su[8];
    __shared__ __align__(16) float s_att[8][NN];  // raw sigmoids (32 KB)
    __shared__ float s_rsum[8][8];
    __shared__ float s_inv[8];

    int h    = blockIdx.x >> 7;
    int i0   = (blockIdx.x & 127) * 8;
    int t    = threadIdx.x;
    int lane = t & 63;
    int wv   = t >> 6;

    // ---------------- phase 1: projections ----------------
    *(float2*)(shm.xs + t * 2) = *(const float2*)(X + i0 * FF + t * 2);
    if (t < FP) s_ae[t] = a[h * FP + t];
    __syncthreads();

    {
        int wsel = wv >> 2;                   // 0: W1 (u), 1: W2 (v)
        int r0   = (wv & 3) * 2;              // two rows per wave
        const float* Wp = (wsel ? W2 : W1) + h * FF * FP;
        const float* x0 = shm.xs + (r0 + 0) * FF;
        const float* x1 = shm.xs + (r0 + 1) * FF;
        float acc0 = 0.f, acc1 = 0.f;
        #pragma unroll 8
        for (int f = 0; f < FF; f += 4) {
            float w0 = Wp[(f + 0) * FP + lane];
            float w1 = Wp[(f + 1) * FP + lane];
            float w2 = Wp[(f + 2) * FP + lane];
            float w3 = Wp[(f + 3) * FP + lane];
            float4 xa = *(const float4*)(x0 + f);
            float4 xb = *(const float4*)(x1 + f);
            acc0 += w0 * xa.x + w1 * xa.y + w2 * xa.z + w3 * xa.w;
            acc1 += w0 * xb.x + w1 * xb.y + w2 * xb.z + w3 * xb.w;
        }
        float be = wsel ? 0.f : b[h * FP + lane];
        float u0 = acc0 + be, u1 = acc1 + be;
        float ae = s_ae[lane];
        float g0 = ae * u0, g1 = ae * u1;
        #pragma unroll
        for (int off = 32; off; off >>= 1) {
            g0 += __shfl_xor(g0, off, 64);
            g1 += __shfl_xor(g1, off, 64);
        }
        if (wsel == 0) {
            s_u[lane][r0] = u0; s_u[lane][r0 + 1] = u1;
            s_h1[r0][lane] = acc0; s_h1[r0 + 1][lane] = acc1;
            if (lane == 0) { s_su[r0] = g0; s_su[r0 + 1] = g1; }
        } else {
            float* VTg = ws + VT_OFF + h * FP * NN;
            *(float2*)(VTg + lane * NN + i0 + r0) = make_float2(u0, u1);
            float* H2g = ws + H2_OFF + (h * NN + i0 + r0) * FP;
            H2g[lane] = acc0; H2g[FP + lane] = acc1;
            if (lane == 0)
                *(float2*)(ws + SV_OFF + h * NN + i0 + r0) = make_float2(g0, g1);
        }
    }

    // ---------------- grid barrier ----------------
    unsigned int* flags = (unsigned int*)(ws + FLAG_OFF);
    __threadfence();
    __syncthreads();
    if (t == 0)
        __hip_atomic_store(&flags[blockIdx.x], GEN, __ATOMIC_RELEASE,
                           __HIP_MEMORY_SCOPE_AGENT);
    if (t < 256) {
        while (__hip_atomic_load(&flags[t], __ATOMIC_ACQUIRE,
                                 __HIP_MEMORY_SCOPE_AGENT) != GEN)
            __builtin_amdgcn_s_sleep(4);
    }
    __syncthreads();

    // ---------------- phase 2: logits + sigmoid + normalize ----------------
    int j2 = t * 2;
    const float* VTp = ws + VT_OFF + h * FP * NN + j2;
    float acc[16];
    #pragma unroll
    for (int k = 0; k < 16; ++k) acc[k] = 0.f;

    #pragma unroll 4
    for (int e = 0; e < FP; ++e) {
        float2 v = *(const float2*)(VTp + e * NN);     // L2 read
        float4 ua = *(const float4*)(&s_u[e][0]);      // LDS broadcast
        float4 ub = *(const float4*)(&s_u[e][4]);
        float ae = s_ae[e];
        float uu[8] = {ua.x, ua.y, ua.z, ua.w, ub.x, ub.y, ub.z, ub.w};
        #pragma unroll
        for (int ii = 0; ii < 8; ++ii) {
            acc[ii * 2 + 0] += ae * fabsf(uu[ii] + v.x);
            acc[ii * 2 + 1] += ae * fabsf(uu[ii] + v.y);
        }
    }

    float2 sv = *(const float2*)(ws + SV_OFF + h * NN + j2);
    float rs[8];
    #pragma unroll
    for (int ii = 0; ii < 8; ++ii) {
        float2 A2 = *(const float2*)(Ad + (i0 + ii) * NN + j2);
        float l0 = 0.6f * (s_su[ii] + sv.x) + 0.4f * acc[ii * 2 + 0];
        float l1 = 0.6f * (s_su[ii] + sv.y) + 0.4f * acc[ii * 2 + 1];
        float s0 = (A2.x != 0.f) ? 1.f / (1.f + __expf(-l0)) : 0.f;
        float s1 = (A2.y != 0.f) ? 1.f / (1.f + __expf(-l1)) : 0.f;
        acc[ii * 2 + 0] = s0;
        acc[ii * 2 + 1] = s1;
        *(float2*)(&s_att[ii][j2]) = make_float2(s0, s1);
        rs[ii] = s0 + s1;
    }
    #pragma unroll
    for (int off = 32; off; off >>= 1) {
        #pragma unroll
        for (int ii = 0; ii < 8; ++ii) rs[ii] += __shfl_xor(rs[ii], off, 64);
    }
    if (lane == 0) {
        #pragma unroll
        for (int ii = 0; ii < 8; ++ii) s_rsum[wv][ii] = rs[ii];
    }
    __syncthreads();
    if (t < 8) {
        float S = 0.f;
        #pragma unroll
        for (int wq = 0; wq < 8; ++wq) S += s_rsum[wq][t];
        s_inv[t] = 1.f / (1.f + S);
    }
    __syncthreads();

    #pragma unroll
    for (int ii = 0; ii < 8; ++ii) {
        float iv = s_inv[ii];
        *(float2*)(att + (h * NN + i0 + ii) * NN + j2) =
            make_float2(acc[ii * 2 + 0] * iv, acc[ii * 2 + 1] * iv);
    }

    // ---------------- compaction + sparse aggregation ----------------
    int cnt = 0;
    #pragma unroll
    for (int c = 0; c < 16; ++c) {
        float val = s_att[wv][c * 64 + lane];
        unsigned long long m = __ballot(val != 0.f);
        if (val != 0.f) {
            int pos = cnt + __popcll(m & ((1ull << lane) - 1ull));
            if (pos < 256) {
                shm.p2.eidx[wv][pos] = c * 64 + lane;
                shm.p2.eval[wv][pos] = val;
            }
        }
        cnt += __popcll(m);
    }
    if (cnt > 256) cnt = 256;

    const float* H2p = ws + H2_OFF + h * NN * FP + lane;
    float agg = 0.f;
    #pragma unroll 4
    for (int k = 0; k < cnt; ++k) {
        agg += shm.p2.eval[wv][k] * H2p[shm.p2.eidx[wv][k] * FP];
    }
    float h1  = s_h1[wv][lane];
    float val = s_inv[wv] * (h1 + agg);
    out[(i0 + wv) * (NH * FP) + h * FP + lane] = fmaxf(val, 0.f);
}

extern "C" void kernel_launch(void* const* d_in, const int* in_sizes, int n_in,
                              void* d_out, int out_size, void* d_ws, size_t ws_size,
                              hipStream_t stream) {
    const float* X  = (const float*)d_in[0];
    const float* A  = (const float*)d_in[1];
    const float* W1 = (const float*)d_in[2];
    const float* W2 = (const float*)d_in[3];
    const float* b  = (const float*)d_in[4];
    const float* a  = (const float*)d_in[5];

    float* out = (float*)d_out;
    float* att = out + NN * NH * FP;   // outputs (out, att) concatenated
    float* ws  = (float*)d_ws;

    kFused<<<256, 512, 0, stream>>>(X, A, W1, W2, b, a, ws, out, att);
}

// Round 6
// 35.115 us; speedup vs baseline: 2.6599x; 2.6599x over previous
//
#include <hip/hip_runtime.h>

#define NN 1024
#define FF 128
#define FP 64
#define NH 2

// ws float offsets (cross-block data lives at MALL coherence point via sc1):
#define VT_OFF 0           // [H][FP][NN]  (X·W2)^T
#define H2_OFF 131072      // [H][NN][FP]  X·W2
#define SV_OFF 262144      // [H][NN]      sv = Σe ae·v
#define FLAG_OFF (1 << 22) // u32 flags at 16 MB into ws
#define GEN 0x9E3779B1u

// Relaxed agent-scope ops: coherent at MALL, NO buffer_wbl2 / buffer_inv.
__device__ __forceinline__ void st_ag2(float* p, float x, float y) {
    union { unsigned long long u; float f[2]; } c;
    c.f[0] = x; c.f[1] = y;
    __hip_atomic_store((unsigned long long*)p, c.u, __ATOMIC_RELAXED,
                       __HIP_MEMORY_SCOPE_AGENT);
}
__device__ __forceinline__ void st_ag1(float* p, float x) {
    union { unsigned u; float f; } c; c.f = x;
    __hip_atomic_store((unsigned*)p, c.u, __ATOMIC_RELAXED,
                       __HIP_MEMORY_SCOPE_AGENT);
}
__device__ __forceinline__ float2 ld_ag2(const float* p) {
    unsigned long long u = __hip_atomic_load((const unsigned long long*)p,
                       __ATOMIC_RELAXED, __HIP_MEMORY_SCOPE_AGENT);
    union { unsigned long long u; float2 f; } c; c.u = u; return c.f;
}
__device__ __forceinline__ float ld_ag1(const float* p) {
    unsigned u = __hip_atomic_load((const unsigned*)p, __ATOMIC_RELAXED,
                                   __HIP_MEMORY_SCOPE_AGENT);
    union { unsigned u; float f; } c; c.u = u; return c.f;
}

// 256 blocks (h x 128 i-tiles of 8) x 512 threads (8 waves).
__global__ __launch_bounds__(512) void kFused(const float* __restrict__ X,
        const float* __restrict__ Ad, const float* __restrict__ W1,
        const float* __restrict__ W2, const float* __restrict__ b,
        const float* __restrict__ a, float* __restrict__ ws,
        float* __restrict__ out, float* __restrict__ att) {
    union Shm {
        float xs[8 * FF];                                     // phase 1 (4 KB)
        struct { float eval[8][256]; int eidx[8][256]; } p2;  // phase 2 (16 KB)
    };
    __shared__ Shm shm;
    __shared__ float s_u[FP][8];
    __shared__ float s_h1[8][FP];
    __shared__ float s_ae[FP];
    __shared__ float s_su[8];
    __shared__ __align__(16) float s_att[8][NN];              // 32 KB
    __shared__ float s_rsum[8][8];
    __shared__ float s_inv[8];

    int h    = blockIdx.x >> 7;
    int i0   = (blockIdx.x & 127) * 8;
    int t    = threadIdx.x;
    int lane = t & 63;
    int wv   = t >> 6;

    // ---------------- phase 1: projections ----------------
    *(float2*)(shm.xs + t * 2) = *(const float2*)(X + i0 * FF + t * 2);
    if (t < FP) s_ae[t] = a[h * FP + t];
    __syncthreads();

    {
        int wsel = wv >> 2;                   // 0: W1 (u-side), 1: W2 (v-side)
        int r0   = (wv & 3) * 2;
        const float* Wp = (wsel ? W2 : W1) + h * FF * FP;
        const float* x0 = shm.xs + (r0 + 0) * FF;
        const float* x1 = shm.xs + (r0 + 1) * FF;
        float acc0 = 0.f, acc1 = 0.f;
        #pragma unroll 8
        for (int f = 0; f < FF; f += 4) {
            float w0 = Wp[(f + 0) * FP + lane];
            float w1 = Wp[(f + 1) * FP + lane];
            float w2 = Wp[(f + 2) * FP + lane];
            float w3 = Wp[(f + 3) * FP + lane];
            float4 xa = *(const float4*)(x0 + f);
            float4 xb = *(const float4*)(x1 + f);
            acc0 += w0 * xa.x + w1 * xa.y + w2 * xa.z + w3 * xa.w;
            acc1 += w0 * xb.x + w1 * xb.y + w2 * xb.z + w3 * xb.w;
        }
        float be = wsel ? 0.f : b[h * FP + lane];
        float u0 = acc0 + be, u1 = acc1 + be;
        float ae = s_ae[lane];
        float g0 = ae * u0, g1 = ae * u1;
        #pragma unroll
        for (int off = 32; off; off >>= 1) {
            g0 += __shfl_xor(g0, off, 64);
            g1 += __shfl_xor(g1, off, 64);
        }
        if (wsel == 0) {
            s_u[lane][r0] = u0; s_u[lane][r0 + 1] = u1;
            s_h1[r0][lane] = acc0; s_h1[r0 + 1][lane] = acc1;
            if (lane == 0) { s_su[r0] = g0; s_su[r0 + 1] = g1; }
        } else {
            // sc1 write-through stores (visible at MALL once vmcnt retires)
            st_ag2(ws + VT_OFF + h * FP * NN + lane * NN + i0 + r0, u0, u1);
            float* H2g = ws + H2_OFF + (h * NN + i0 + r0) * FP;
            st_ag1(H2g + lane, acc0);
            st_ag1(H2g + FP + lane, acc1);
            if (lane == 0)
                st_ag2(ws + SV_OFF + h * NN + i0 + r0, g0, g1);
        }
    }

    // ---------------- grid barrier (no wbl2 / no buffer_inv) --------------
    // __syncthreads drains every wave's vmcnt -> all sc1 stores are at MALL.
    __syncthreads();
    unsigned int* flags = (unsigned int*)(ws + FLAG_OFF);
    if (t == 0)
        __hip_atomic_store(&flags[blockIdx.x], GEN, __ATOMIC_RELAXED,
                           __HIP_MEMORY_SCOPE_AGENT);
    if (t < 256) {
        while (__hip_atomic_load(&flags[t], __ATOMIC_RELAXED,
                                 __HIP_MEMORY_SCOPE_AGENT) != GEN)
            __builtin_amdgcn_s_sleep(4);
    }
    asm volatile("" ::: "memory");
    __syncthreads();

    // ---------------- phase 2: logits + sigmoid + normalize ---------------
    int j2 = t * 2;
    // prefetch A rows + sv (HBM/MALL latency hides under the 64-e loop)
    float2 A2r[8];
    #pragma unroll
    for (int ii = 0; ii < 8; ++ii)
        A2r[ii] = *(const float2*)(Ad + (i0 + ii) * NN + j2);
    float2 sv = ld_ag2(ws + SV_OFF + h * NN + j2);

    const float* VTp = ws + VT_OFF + h * FP * NN + j2;
    float acc[16];
    #pragma unroll
    for (int k = 0; k < 16; ++k) acc[k] = 0.f;

    #pragma unroll 8
    for (int e = 0; e < FP; ++e) {
        float2 v = ld_ag2(VTp + e * NN);               // sc1, MALL-coherent
        float4 ua = *(const float4*)(&s_u[e][0]);
        float4 ub = *(const float4*)(&s_u[e][4]);
        float ae = s_ae[e];
        float uu[8] = {ua.x, ua.y, ua.z, ua.w, ub.x, ub.y, ub.z, ub.w};
        #pragma unroll
        for (int ii = 0; ii < 8; ++ii) {
            acc[ii * 2 + 0] += ae * fabsf(uu[ii] + v.x);
            acc[ii * 2 + 1] += ae * fabsf(uu[ii] + v.y);
        }
    }

    float rs[8];
    #pragma unroll
    for (int ii = 0; ii < 8; ++ii) {
        float l0 = 0.6f * (s_su[ii] + sv.x) + 0.4f * acc[ii * 2 + 0];
        float l1 = 0.6f * (s_su[ii] + sv.y) + 0.4f * acc[ii * 2 + 1];
        float s0 = (A2r[ii].x != 0.f) ? 1.f / (1.f + __expf(-l0)) : 0.f;
        float s1 = (A2r[ii].y != 0.f) ? 1.f / (1.f + __expf(-l1)) : 0.f;
        acc[ii * 2 + 0] = s0;
        acc[ii * 2 + 1] = s1;
        *(float2*)(&s_att[ii][j2]) = make_float2(s0, s1);
        rs[ii] = s0 + s1;
    }
    #pragma unroll
    for (int off = 32; off; off >>= 1) {
        #pragma unroll
        for (int ii = 0; ii < 8; ++ii) rs[ii] += __shfl_xor(rs[ii], off, 64);
    }
    if (lane == 0) {
        #pragma unroll
        for (int ii = 0; ii < 8; ++ii) s_rsum[wv][ii] = rs[ii];
    }
    __syncthreads();
    if (t < 8) {
        float S = 0.f;
        #pragma unroll
        for (int wq = 0; wq < 8; ++wq) S += s_rsum[wq][t];
        s_inv[t] = 1.f / (1.f + S);
    }
    __syncthreads();

    #pragma unroll
    for (int ii = 0; ii < 8; ++ii) {
        float iv = s_inv[ii];
        *(float2*)(att + (h * NN + i0 + ii) * NN + j2) =
            make_float2(acc[ii * 2 + 0] * iv, acc[ii * 2 + 1] * iv);
    }

    // ---------------- compaction + sparse aggregation ----------------
    int cnt = 0;
    #pragma unroll
    for (int c = 0; c < 16; ++c) {
        float val = s_att[wv][c * 64 + lane];
        unsigned long long m = __ballot(val != 0.f);
        if (val != 0.f) {
            int pos = cnt + __popcll(m & ((1ull << lane) - 1ull));
            if (pos < 256) {
                shm.p2.eidx[wv][pos] = c * 64 + lane;
                shm.p2.eval[wv][pos] = val;
            }
        }
        cnt += __popcll(m);
    }
    if (cnt > 256) cnt = 256;

    const float* H2p = ws + H2_OFF + h * NN * FP + lane;
    float agg = 0.f;
    #pragma unroll 4
    for (int k = 0; k < cnt; ++k) {
        agg += shm.p2.eval[wv][k] * ld_ag1(H2p + shm.p2.eidx[wv][k] * FP);
    }
    float h1  = s_h1[wv][lane];
    float val = s_inv[wv] * (h1 + agg);
    out[(i0 + wv) * (NH * FP) + h * FP + lane] = fmaxf(val, 0.f);
}

extern "C" void kernel_launch(void* const* d_in, const int* in_sizes, int n_in,
                              void* d_out, int out_size, void* d_ws, size_t ws_size,
                              hipStream_t stream) {
    const float* X  = (const float*)d_in[0];
    const float* A  = (const float*)d_in[1];
    const float* W1 = (const float*)d_in[2];
    const float* W2 = (const float*)d_in[3];
    const float* b  = (const float*)d_in[4];
    const float* a  = (const float*)d_in[5];

    float* out = (float*)d_out;
    float* att = out + NN * NH * FP;   // outputs (out, att) concatenated
    float* ws  = (float*)d_ws;

    kFused<<<256, 512, 0, stream>>>(X, A, W1, W2, b, a, ws, out, att);
}